// Round 4
// baseline (416.055 us; speedup 1.0000x reference)
//
#include <hip/hip_runtime.h>

// ---------------------------------------------------------------------------
// 3-layer GCN. Factorized: tmp[n] = dinv[n]*(h[n]@W); agg[i]=dinv[i]*(tmp[i]+sum tmp[src])+b
// All fp32 (threshold is ~1e-5 relative of max|out|~488; bf16 forbidden).
// GEMM v4: lane=row, wave-uniform W column slice -> W via uniform (SMEM/broadcast)
// loads, zero W-LDS traffic. A staged global_load_lds + XOR chunk swizzle.
// ---------------------------------------------------------------------------

// ---------------- CSR build ----------------

__global__ __launch_bounds__(256) void count_kernel(const int* __restrict__ dst,
                                                    int* __restrict__ cnt, int E) {
    int e = blockIdx.x * 256 + threadIdx.x;
    if (e < E) atomicAdd(&cnt[dst[e]], 1);
}

__global__ __launch_bounds__(256) void dinv_kernel(const int* __restrict__ cnt,
                                                   float* __restrict__ dinv, int M) {
    int i = blockIdx.x * 256 + threadIdx.x;
    if (i < M) dinv[i] = 1.0f / sqrtf((float)cnt[i] + 1.0f);  // +1: self-loop
}

__global__ __launch_bounds__(256) void scan1_kernel(const int* __restrict__ cnt,
                                                    int* __restrict__ loc,
                                                    int* __restrict__ bsum, int M) {
    __shared__ int sm[256];
    int t = threadIdx.x;
    int i = blockIdx.x * 256 + t;
    int v = (i < M) ? cnt[i] : 0;
    sm[t] = v;
    __syncthreads();
    for (int o = 1; o < 256; o <<= 1) {
        int add = (t >= o) ? sm[t - o] : 0;
        __syncthreads();
        sm[t] += add;
        __syncthreads();
    }
    if (i < M) loc[i] = sm[t] - v;
    if (t == 255) bsum[blockIdx.x] = sm[255];
}

__global__ __launch_bounds__(256) void scan2_kernel(int* __restrict__ bsum, int NB) {
    __shared__ int sm[256];
    int t = threadIdx.x;
    int v = (t < NB) ? bsum[t] : 0;
    sm[t] = v;
    __syncthreads();
    for (int o = 1; o < 256; o <<= 1) {
        int add = (t >= o) ? sm[t - o] : 0;
        __syncthreads();
        sm[t] += add;
        __syncthreads();
    }
    if (t < NB) bsum[t] = sm[t] - v;
}

__global__ __launch_bounds__(256) void place_kernel(const int* __restrict__ src,
                                                    const int* __restrict__ dst,
                                                    const int* __restrict__ loc,
                                                    const int* __restrict__ base,
                                                    int* __restrict__ fill,
                                                    int* __restrict__ srcs, int E) {
    int e = blockIdx.x * 256 + threadIdx.x;
    if (e >= E) return;
    int d = dst[e];
    int pos = loc[d] + base[d >> 8] + atomicAdd(&fill[d], 1);
    srcs[pos] = src[e];
}

// ---------------- GEMM v4 ----------------
// Block: 256 threads = 4 waves, 64 rows (lane = row), each wave owns CW columns.
// 4*CW == C. W read with fully-uniform addresses (c0 via readfirstlane) ->
// SMEM/broadcast, no LDS. A: [64][KB=64] LDS tile, chunk-swizzled both sides.
// Epilogue: LDS transpose (swizzled) -> coalesced global stores.

__device__ __forceinline__ void gload_lds16(const float* g, float* l) {
    __builtin_amdgcn_global_load_lds((const __attribute__((address_space(1))) void*)g,
                                     (__attribute__((address_space(3))) void*)l,
                                     16, 0, 0);
}

template <int K, int C, int CW>
__global__ __launch_bounds__(256) void gemm_v4(const float* __restrict__ A,
                                               const float* __restrict__ W,
                                               const float* __restrict__ dinv,
                                               float* __restrict__ out, int M) {
    constexpr int KB = 64;            // A k-chunk (floats per row)
    constexpr int NCH = K / KB;       // chunks
    constexpr int NW4 = CW / 4;       // float4 per W set
    static_assert(4 * CW == C, "4 waves cover C");

    // 2 x [64][KB] A buffers = 32 KB; reused as [64][C] for the store transpose.
    __shared__ __align__(16) float lds[2 * 64 * KB];

    const int t = threadIdx.x;
    const int lane = t & 63;
    const int wv = __builtin_amdgcn_readfirstlane(t >> 6);
    const int c0 = wv * CW;
    const int row0 = blockIdx.x * 64;
    const int row = row0 + lane;

    auto stage = [&](int ch, int buf) {
        const int k0 = ch * KB;
        float* dst = lds + buf * 64 * KB;
#pragma unroll
        for (int rnd = 0; rnd < 4; ++rnd) {
            int L = rnd * 256 + t;
            int r = L >> 4;                 // row in tile (16 16B-chunks per row)
            int cp = L & 15;                // LDS chunk
            int gc = cp ^ (r & 7);          // global chunk (inverse swizzle)
            int grow = row0 + r;
            if (grow >= M) grow = M - 1;
            gload_lds16(A + (size_t)grow * K + k0 + gc * 4, dst + L * 4);
        }
    };

    float acc[CW];
#pragma unroll
    for (int j = 0; j < CW; ++j) acc[j] = 0.f;

    const float* Wc = W + c0;           // uniform column base

    float4 wA[NW4], wB[NW4];
    auto wload = [&](float4* dw, int k) {
#pragma unroll
        for (int j = 0; j < NW4; ++j)
            dw[j] = *(const float4*)(Wc + (size_t)k * C + j * 4);
    };
    auto fmas = [&](float av, const float4* w) {
#pragma unroll
        for (int j = 0; j < NW4; ++j) {
            acc[j * 4 + 0] += av * w[j].x;
            acc[j * 4 + 1] += av * w[j].y;
            acc[j * 4 + 2] += av * w[j].z;
            acc[j * 4 + 3] += av * w[j].w;
        }
    };

    stage(0, 0);
    wload(wA, 0);
    __syncthreads();

    for (int ch = 0; ch < NCH; ++ch) {
        if (ch + 1 < NCH) stage(ch + 1, (ch + 1) & 1);
        const float* Abuf = lds + (ch & 1) * 64 * KB;
        for (int kc = 0; kc < KB / 4; ++kc) {
            const int kb = ch * KB + kc * 4;
            float4 a4 = *(const float4*)&Abuf[lane * KB + ((kc ^ (lane & 7)) << 2)];
            wload(wB, kb + 1);
            fmas(a4.x, wA);
            wload(wA, kb + 2);
            fmas(a4.y, wB);
            wload(wB, kb + 3);
            fmas(a4.z, wA);
            if (kb + 4 < K) wload(wA, kb + 4);
            fmas(a4.w, wB);
        }
        __syncthreads();   // next A buffer staged (drains vmcnt)
    }

    // ---- epilogue: scale by dinv, LDS transpose (swizzled), coalesced store ----
    {
        int rr = row < M ? row : M - 1;
        float dv = dinv[rr];
        float* T = lds;                       // [64][C]
        const int cb = c0 >> 2;               // first f4-chunk of this wave's slice
#pragma unroll
        for (int j = 0; j < NW4; ++j) {
            int pos = (cb + j) ^ (lane & 7);  // swizzled chunk position
            float4 v = make_float4(acc[j * 4 + 0] * dv, acc[j * 4 + 1] * dv,
                                   acc[j * 4 + 2] * dv, acc[j * 4 + 3] * dv);
            *(float4*)&T[lane * C + pos * 4] = v;
        }
        __syncthreads();
        constexpr int CH = C / 4;             // f4-chunks per row
        constexpr int RPB = 256 / CH;         // rows handled per round
#pragma unroll
        for (int rnd = 0; rnd < 64 / RPB; ++rnd) {
            int r = rnd * RPB + t / CH;
            int jc = t % CH;
            int grow = row0 + r;
            if (grow < M) {
                float4 v = *(const float4*)&T[r * C + (jc ^ (r & 7)) * 4];
                *(float4*)(out + (size_t)grow * C + jc * 4) = v;
            }
        }
    }
}

// ---------------- Aggregation: out[i] = act(dinv[i]*(tmp[i] + sum tmp[src]) + b) ----------------

template <int C, bool RELU>
__global__ __launch_bounds__(256) void agg_kernel(const float* __restrict__ tmp,
                                                  const int* __restrict__ srcs,
                                                  const int* __restrict__ cnt,
                                                  const int* __restrict__ loc,
                                                  const int* __restrict__ base,
                                                  const float* __restrict__ dinv,
                                                  const float* __restrict__ bias,
                                                  float* __restrict__ out, int M) {
    constexpr int TPN = C / 4;        // threads per node (float4 per thread)
    constexpr int NPB = 256 / TPN;    // nodes per block
    const int t = threadIdx.x;
    const int cq = t % TPN;
    const int node = blockIdx.x * NPB + t / TPN;
    if (node >= M) return;

    const float4* tmp4 = (const float4*)tmp;
    float4 acc = tmp4[(size_t)node * TPN + cq];   // self-loop term
    float4 acc2 = make_float4(0.f, 0.f, 0.f, 0.f);
    const int start = loc[node] + base[node >> 8];
    const int n = cnt[node];
    const int* sp = srcs + start;

    const int jn = n & ~3;
    int s0 = 0, s1 = 0, s2 = 0, s3 = 0;
    if (jn > 0) { s0 = sp[0]; s1 = sp[1]; s2 = sp[2]; s3 = sp[3]; }
    for (int j = 0; j < jn; j += 4) {
        float4 v0 = tmp4[(size_t)s0 * TPN + cq];
        float4 v1 = tmp4[(size_t)s1 * TPN + cq];
        float4 v2 = tmp4[(size_t)s2 * TPN + cq];
        float4 v3 = tmp4[(size_t)s3 * TPN + cq];
        if (j + 4 < jn) {
            s0 = sp[j + 4]; s1 = sp[j + 5]; s2 = sp[j + 6]; s3 = sp[j + 7];
        }
        acc.x  += v0.x + v1.x;  acc.y  += v0.y + v1.y;
        acc.z  += v0.z + v1.z;  acc.w  += v0.w + v1.w;
        acc2.x += v2.x + v3.x;  acc2.y += v2.y + v3.y;
        acc2.z += v2.z + v3.z;  acc2.w += v2.w + v3.w;
    }
    for (int j = jn; j < n; ++j) {
        float4 v = tmp4[(size_t)sp[j] * TPN + cq];
        acc.x += v.x; acc.y += v.y; acc.z += v.z; acc.w += v.w;
    }
    acc.x += acc2.x; acc.y += acc2.y; acc.z += acc2.z; acc.w += acc2.w;

    float dv = dinv[node];
    float4 b = *(const float4*)(bias + cq * 4);
    float4 r;
    r.x = acc.x * dv + b.x;
    r.y = acc.y * dv + b.y;
    r.z = acc.z * dv + b.z;
    r.w = acc.w * dv + b.w;
    if (RELU) {
        r.x = fmaxf(r.x, 0.f); r.y = fmaxf(r.y, 0.f);
        r.z = fmaxf(r.z, 0.f); r.w = fmaxf(r.w, 0.f);
    }
    ((float4*)out)[(size_t)node * TPN + cq] = r;
}

// ---------------- launch ----------------

extern "C" void kernel_launch(void* const* d_in, const int* in_sizes, int n_in,
                              void* d_out, int out_size, void* d_ws, size_t ws_size,
                              hipStream_t stream) {
    const float* x  = (const float*)d_in[0];
    const int*   ei = (const int*)d_in[1];
    const float* W1 = (const float*)d_in[2];
    const float* b1 = (const float*)d_in[3];
    const float* W2 = (const float*)d_in[4];
    const float* b2 = (const float*)d_in[5];
    const float* W3 = (const float*)d_in[6];
    const float* b3 = (const float*)d_in[7];
    float* out = (float*)d_out;

    const int M = in_sizes[0] / 256;   // 50000 nodes
    const int E = in_sizes[1] / 2;     // 800000 edges
    const int NB = (M + 255) / 256;

    char* p = (char*)d_ws;
    auto alloc = [&](size_t bytes) {
        char* r = p;
        p += (bytes + 255) & ~(size_t)255;
        return r;
    };
    int*   cnt  = (int*)alloc((size_t)M * 4);
    int*   fill = (int*)alloc((size_t)M * 4);
    int*   loc  = (int*)alloc((size_t)M * 4);
    int*   base = (int*)alloc((size_t)NB * 4);
    float* dinv = (float*)alloc((size_t)M * 4);
    int*   srcs = (int*)alloc((size_t)E * 4);
    float* tmp  = (float*)alloc((size_t)M * 128 * 4);
    float* h    = (float*)alloc((size_t)M * 128 * 4);

    hipMemsetAsync(cnt, 0, (size_t)M * 4, stream);
    hipMemsetAsync(fill, 0, (size_t)M * 4, stream);

    const int* esrc = ei;
    const int* edst = ei + E;

    count_kernel<<<(E + 255) / 256, 256, 0, stream>>>(edst, cnt, E);
    dinv_kernel<<<(M + 255) / 256, 256, 0, stream>>>(cnt, dinv, M);
    scan1_kernel<<<NB, 256, 0, stream>>>(cnt, loc, base, M);
    scan2_kernel<<<1, 256, 0, stream>>>(base, NB);
    place_kernel<<<(E + 255) / 256, 256, 0, stream>>>(esrc, edst, loc, base, fill, srcs, E);

    const int gemm_grid = (M + 63) / 64;   // 782

    // layer 1: x[50000,256] @ W1[256,128] -> relu agg -> h
    gemm_v4<256, 128, 32><<<gemm_grid, 256, 0, stream>>>(x, W1, dinv, tmp, M);
    agg_kernel<128, true><<<(M + 7) / 8, 256, 0, stream>>>(tmp, srcs, cnt, loc, base, dinv, b1, h, M);

    // layer 2: h @ W2[128,128] -> relu agg -> h
    gemm_v4<128, 128, 32><<<gemm_grid, 256, 0, stream>>>(h, W2, dinv, tmp, M);
    agg_kernel<128, true><<<(M + 7) / 8, 256, 0, stream>>>(tmp, srcs, cnt, loc, base, dinv, b2, h, M);

    // layer 3: h @ W3[128,64] -> agg -> out
    gemm_v4<128, 64, 16><<<gemm_grid, 256, 0, stream>>>(h, W3, dinv, tmp, M);
    agg_kernel<64, false><<<(M + 15) / 16, 256, 0, stream>>>(tmp, srcs, cnt, loc, base, dinv, b3, out, M);
}

// Round 5
// 377.740 us; speedup vs baseline: 1.1014x; 1.1014x over previous
//
#include <hip/hip_runtime.h>

// ---------------------------------------------------------------------------
// 3-layer GCN. Factorized: tmp[n] = dinv[n]*(h[n]@W); agg[i]=dinv[i]*(tmp[i]+sum tmp[src])+b
// All fp32 (threshold ~1e-5 relative of max|out|~488; bf16 forbidden).
// GEMM v5: 1-wave blocks (no barrier convoy), 64-row x C tile, 16x8 / 8x8
// thread tile, KB=16 double-buffered via global_load_lds, bank-exact swizzle.
// ---------------------------------------------------------------------------

// ---------------- CSR build ----------------

__global__ __launch_bounds__(256) void count_kernel(const int* __restrict__ dst,
                                                    int* __restrict__ cnt, int E) {
    int e = blockIdx.x * 256 + threadIdx.x;
    if (e < E) atomicAdd(&cnt[dst[e]], 1);
}

__global__ __launch_bounds__(256) void dinv_kernel(const int* __restrict__ cnt,
                                                   float* __restrict__ dinv, int M) {
    int i = blockIdx.x * 256 + threadIdx.x;
    if (i < M) dinv[i] = 1.0f / sqrtf((float)cnt[i] + 1.0f);  // +1: self-loop
}

__global__ __launch_bounds__(256) void scan1_kernel(const int* __restrict__ cnt,
                                                    int* __restrict__ loc,
                                                    int* __restrict__ bsum, int M) {
    __shared__ int sm[256];
    int t = threadIdx.x;
    int i = blockIdx.x * 256 + t;
    int v = (i < M) ? cnt[i] : 0;
    sm[t] = v;
    __syncthreads();
    for (int o = 1; o < 256; o <<= 1) {
        int add = (t >= o) ? sm[t - o] : 0;
        __syncthreads();
        sm[t] += add;
        __syncthreads();
    }
    if (i < M) loc[i] = sm[t] - v;
    if (t == 255) bsum[blockIdx.x] = sm[255];
}

__global__ __launch_bounds__(256) void scan2_kernel(int* __restrict__ bsum, int NB) {
    __shared__ int sm[256];
    int t = threadIdx.x;
    int v = (t < NB) ? bsum[t] : 0;
    sm[t] = v;
    __syncthreads();
    for (int o = 1; o < 256; o <<= 1) {
        int add = (t >= o) ? sm[t - o] : 0;
        __syncthreads();
        sm[t] += add;
        __syncthreads();
    }
    if (t < NB) bsum[t] = sm[t] - v;
}

__global__ __launch_bounds__(256) void place_kernel(const int* __restrict__ src,
                                                    const int* __restrict__ dst,
                                                    const int* __restrict__ loc,
                                                    const int* __restrict__ base,
                                                    int* __restrict__ fill,
                                                    int* __restrict__ srcs, int E) {
    int e = blockIdx.x * 256 + threadIdx.x;
    if (e >= E) return;
    int d = dst[e];
    int pos = loc[d] + base[d >> 8] + atomicAdd(&fill[d], 1);
    srcs[pos] = src[e];
}

// ---------------- GEMM v5 ----------------
// 64 threads = 1 wave per block. Tile: 64 rows x C cols.
// CT = C/8 col-groups (tx), each thread: RN=8 cols as two quads {tx*4, C/2+tx*4}.
// G = 64/CT row-groups (ty); RM = CT rows per thread, row = ty + G*i (interleaved).
// KB=16 k-chunk, double-buffered, staged by global_load_lds (w=16).
// A tile [64][16] chunk-swizzled: lds chunk (r,cp) holds global chunk cp^(r&3).

__device__ __forceinline__ void gload_lds16(const float* g, float* l) {
    __builtin_amdgcn_global_load_lds((const __attribute__((address_space(1))) void*)g,
                                     (__attribute__((address_space(3))) void*)l,
                                     16, 0, 0);
}

template <int K, int C>
__global__ __launch_bounds__(64) void gemm_v5(const float* __restrict__ A,
                                              const float* __restrict__ W,
                                              const float* __restrict__ dinv,
                                              float* __restrict__ out, int M) {
    constexpr int KB = 16;
    constexpr int CT = C / 8;          // col groups (16 for C=128, 8 for C=64)
    constexpr int G  = 64 / CT;        // row groups (4 / 8)
    constexpr int RM = CT;             // rows per thread (16 / 8)
    constexpr int NCH = K / KB;
    constexpr int AW = 64 * KB;        // floats per A buffer (1024)
    constexpr int WW = KB * C;         // floats per W buffer (2048 / 1024)
    constexpr int WRND = WW / 4 / 64;  // W stage rounds (8 / 4)

    __shared__ __align__(16) float Ab[2][AW];
    __shared__ __align__(16) float Wb[2][WW];

    const int t = threadIdx.x;         // 0..63 (= lane)
    const int tx = t % CT;
    const int ty = t / CT;             // 0..G-1
    const int row0 = blockIdx.x * 64;

    auto stage = [&](int ch, int buf) {
        const int k0 = ch * KB;
        // A: 64 rows x 4 chunks = 256 chunks -> 4 rounds
#pragma unroll
        for (int rnd = 0; rnd < 4; ++rnd) {
            int L = rnd * 64 + t;
            int r = L >> 2;
            int cp = L & 3;
            int gc = cp ^ (r & 3);          // inverse swizzle on global source
            int grow = row0 + r;
            if (grow >= M) grow = M - 1;    // clamped rows never stored
            gload_lds16(A + (size_t)grow * K + k0 + gc * 4, &Ab[buf][L * 4]);
        }
        // W chunk: contiguous, linear
#pragma unroll
        for (int rnd = 0; rnd < WRND; ++rnd) {
            int L = rnd * 64 + t;
            gload_lds16(W + (size_t)k0 * C + L * 4, &Wb[buf][L * 4]);
        }
    };

    float acc[RM][8];
#pragma unroll
    for (int i = 0; i < RM; ++i)
#pragma unroll
        for (int j = 0; j < 8; ++j) acc[i][j] = 0.f;

    stage(0, 0);
    __syncthreads();

    for (int ch = 0; ch < NCH; ++ch) {
        if (ch + 1 < NCH) stage(ch + 1, (ch + 1) & 1);
        const float* Abuf = Ab[ch & 1];
        const float* Wbuf = Wb[ch & 1];
#pragma unroll
        for (int kq = 0; kq < KB / 4; ++kq) {
            float4 a[RM];
#pragma unroll
            for (int i = 0; i < RM; ++i) {
                int r = ty + G * i;
                a[i] = *(const float4*)&Abuf[r * KB + ((kq ^ (r & 3)) << 2)];
            }
#pragma unroll
            for (int kk = 0; kk < 4; ++kk) {
                const int k = kq * 4 + kk;
                float4 w0 = *(const float4*)&Wbuf[k * C + tx * 4];
                float4 w1 = *(const float4*)&Wbuf[k * C + C / 2 + tx * 4];
#pragma unroll
                for (int i = 0; i < RM; ++i) {
                    float av = (&a[i].x)[kk];
                    acc[i][0] += av * w0.x; acc[i][1] += av * w0.y;
                    acc[i][2] += av * w0.z; acc[i][3] += av * w0.w;
                    acc[i][4] += av * w1.x; acc[i][5] += av * w1.y;
                    acc[i][6] += av * w1.z; acc[i][7] += av * w1.w;
                }
            }
        }
        __syncthreads();   // 1-wave block: waitcnt drain, no convoy
    }

#pragma unroll
    for (int i = 0; i < RM; ++i) {
        int r = row0 + ty + G * i;
        if (r < M) {
            float dv = dinv[r];
            float4 v0 = make_float4(acc[i][0] * dv, acc[i][1] * dv,
                                    acc[i][2] * dv, acc[i][3] * dv);
            float4 v1 = make_float4(acc[i][4] * dv, acc[i][5] * dv,
                                    acc[i][6] * dv, acc[i][7] * dv);
            *(float4*)(out + (size_t)r * C + tx * 4) = v0;
            *(float4*)(out + (size_t)r * C + C / 2 + tx * 4) = v1;
        }
    }
}

// ---------------- Aggregation: out[i] = act(dinv[i]*(tmp[i] + sum tmp[src]) + b) ----------------
// Unroll x8 with index prefetch: 8 independent gathers in flight per thread.

template <int C, bool RELU>
__global__ __launch_bounds__(256) void agg_kernel(const float* __restrict__ tmp,
                                                  const int* __restrict__ srcs,
                                                  const int* __restrict__ cnt,
                                                  const int* __restrict__ loc,
                                                  const int* __restrict__ base,
                                                  const float* __restrict__ dinv,
                                                  const float* __restrict__ bias,
                                                  float* __restrict__ out, int M) {
    constexpr int TPN = C / 4;        // threads per node (float4 per thread)
    constexpr int NPB = 256 / TPN;    // nodes per block
    const int t = threadIdx.x;
    const int cq = t % TPN;
    const int node = blockIdx.x * NPB + t / TPN;
    if (node >= M) return;

    const float4* tmp4 = (const float4*)tmp;
    float4 acc = tmp4[(size_t)node * TPN + cq];   // self-loop term
    float4 acc2 = make_float4(0.f, 0.f, 0.f, 0.f);
    const int start = loc[node] + base[node >> 8];
    const int n = cnt[node];
    const int* sp = srcs + start;

    const int jn = n & ~7;
    int s[8];
    if (jn > 0) {
#pragma unroll
        for (int u = 0; u < 8; ++u) s[u] = sp[u];
    }
    for (int j = 0; j < jn; j += 8) {
        float4 v0 = tmp4[(size_t)s[0] * TPN + cq];
        float4 v1 = tmp4[(size_t)s[1] * TPN + cq];
        float4 v2 = tmp4[(size_t)s[2] * TPN + cq];
        float4 v3 = tmp4[(size_t)s[3] * TPN + cq];
        float4 v4 = tmp4[(size_t)s[4] * TPN + cq];
        float4 v5 = tmp4[(size_t)s[5] * TPN + cq];
        float4 v6 = tmp4[(size_t)s[6] * TPN + cq];
        float4 v7 = tmp4[(size_t)s[7] * TPN + cq];
        if (j + 8 < jn) {
#pragma unroll
            for (int u = 0; u < 8; ++u) s[u] = sp[j + 8 + u];
        }
        acc.x  += v0.x + v1.x;  acc.y  += v0.y + v1.y;
        acc.z  += v0.z + v1.z;  acc.w  += v0.w + v1.w;
        acc2.x += v2.x + v3.x;  acc2.y += v2.y + v3.y;
        acc2.z += v2.z + v3.z;  acc2.w += v2.w + v3.w;
        acc.x  += v4.x + v5.x;  acc.y  += v4.y + v5.y;
        acc.z  += v4.z + v5.z;  acc.w  += v4.w + v5.w;
        acc2.x += v6.x + v7.x;  acc2.y += v6.y + v7.y;
        acc2.z += v6.z + v7.z;  acc2.w += v6.w + v7.w;
    }
    for (int j = jn; j < n; ++j) {
        float4 v = tmp4[(size_t)sp[j] * TPN + cq];
        acc.x += v.x; acc.y += v.y; acc.z += v.z; acc.w += v.w;
    }
    acc.x += acc2.x; acc.y += acc2.y; acc.z += acc2.z; acc.w += acc2.w;

    float dv = dinv[node];
    float4 b = *(const float4*)(bias + cq * 4);
    float4 r;
    r.x = acc.x * dv + b.x;
    r.y = acc.y * dv + b.y;
    r.z = acc.z * dv + b.z;
    r.w = acc.w * dv + b.w;
    if (RELU) {
        r.x = fmaxf(r.x, 0.f); r.y = fmaxf(r.y, 0.f);
        r.z = fmaxf(r.z, 0.f); r.w = fmaxf(r.w, 0.f);
    }
    ((float4*)out)[(size_t)node * TPN + cq] = r;
}

// ---------------- launch ----------------

extern "C" void kernel_launch(void* const* d_in, const int* in_sizes, int n_in,
                              void* d_out, int out_size, void* d_ws, size_t ws_size,
                              hipStream_t stream) {
    const float* x  = (const float*)d_in[0];
    const int*   ei = (const int*)d_in[1];
    const float* W1 = (const float*)d_in[2];
    const float* b1 = (const float*)d_in[3];
    const float* W2 = (const float*)d_in[4];
    const float* b2 = (const float*)d_in[5];
    const float* W3 = (const float*)d_in[6];
    const float* b3 = (const float*)d_in[7];
    float* out = (float*)d_out;

    const int M = in_sizes[0] / 256;   // 50000 nodes
    const int E = in_sizes[1] / 2;     // 800000 edges
    const int NB = (M + 255) / 256;

    char* p = (char*)d_ws;
    auto alloc = [&](size_t bytes) {
        char* r = p;
        p += (bytes + 255) & ~(size_t)255;
        return r;
    };
    int*   cnt  = (int*)alloc((size_t)M * 4);
    int*   fill = (int*)alloc((size_t)M * 4);
    int*   loc  = (int*)alloc((size_t)M * 4);
    int*   base = (int*)alloc((size_t)NB * 4);
    float* dinv = (float*)alloc((size_t)M * 4);
    int*   srcs = (int*)alloc((size_t)E * 4);
    float* tmp  = (float*)alloc((size_t)M * 128 * 4);
    float* h    = (float*)alloc((size_t)M * 128 * 4);

    hipMemsetAsync(cnt, 0, (size_t)M * 4, stream);
    hipMemsetAsync(fill, 0, (size_t)M * 4, stream);

    const int* esrc = ei;
    const int* edst = ei + E;

    count_kernel<<<(E + 255) / 256, 256, 0, stream>>>(edst, cnt, E);
    dinv_kernel<<<(M + 255) / 256, 256, 0, stream>>>(cnt, dinv, M);
    scan1_kernel<<<NB, 256, 0, stream>>>(cnt, loc, base, M);
    scan2_kernel<<<1, 256, 0, stream>>>(base, NB);
    place_kernel<<<(E + 255) / 256, 256, 0, stream>>>(esrc, edst, loc, base, fill, srcs, E);

    const int gemm_grid = (M + 63) / 64;   // 782

    // layer 1: x[50000,256] @ W1[256,128] -> relu agg -> h
    gemm_v5<256, 128><<<gemm_grid, 64, 0, stream>>>(x, W1, dinv, tmp, M);
    agg_kernel<128, true><<<(M + 7) / 8, 256, 0, stream>>>(tmp, srcs, cnt, loc, base, dinv, b1, h, M);

    // layer 2: h @ W2[128,128] -> relu agg -> h
    gemm_v5<128, 128><<<gemm_grid, 64, 0, stream>>>(h, W2, dinv, tmp, M);
    agg_kernel<128, true><<<(M + 7) / 8, 256, 0, stream>>>(tmp, srcs, cnt, loc, base, dinv, b2, h, M);

    // layer 3: h @ W3[128,64] -> agg -> out
    gemm_v5<128, 64><<<gemm_grid, 64, 0, stream>>>(h, W3, dinv, tmp, M);
    agg_kernel<64, false><<<(M + 15) / 16, 256, 0, stream>>>(tmp, srcs, cnt, loc, base, dinv, b3, out, M);
}